// Round 3
// baseline (167.462 us; speedup 1.0000x reference)
//
#include <hip/hip_runtime.h>

typedef _Float16 f16x8 __attribute__((ext_vector_type(8)));
typedef float f32x4 __attribute__((ext_vector_type(4)));

#define B_  8
#define LQ  2048
#define LC  4096
#define DD  256

// async global->LDS, 16B per lane. LDS dest is wave-uniform base + lane*16.
__device__ __forceinline__ void gload_lds16(const void* g, void* l) {
    __builtin_amdgcn_global_load_lds(
        (const __attribute__((address_space(1))) unsigned int*)g,
        (__attribute__((address_space(3))) unsigned int*)l,
        16, 0, 0);
}

// Fused f32->f16 convert: query then context, 8 floats/thread.
__global__ __launch_bounds__(256)
void convert_all(const float* __restrict__ q, const float* __restrict__ c,
                 _Float16* __restrict__ qf, _Float16* __restrict__ cf) {
    const int NQ = B_ * LQ * DD;                  // 4,194,304 (2048 blocks' worth)
    const int i  = (blockIdx.x * 256 + threadIdx.x) * 8;
    const float* src;
    _Float16*    dst;
    if (i < NQ) { src = q + i;      dst = qf + i; }
    else        { src = c + (i - NQ); dst = cf + (i - NQ); }
    const float4 v0 = *(const float4*)(src);
    const float4 v1 = *(const float4*)(src + 4);
    f16x8 o;
    o[0] = (_Float16)v0.x; o[1] = (_Float16)v0.y;
    o[2] = (_Float16)v0.z; o[3] = (_Float16)v0.w;
    o[4] = (_Float16)v1.x; o[5] = (_Float16)v1.y;
    o[6] = (_Float16)v1.z; o[7] = (_Float16)v1.w;
    *(f16x8*)(dst) = o;
}

// One block per (b, 128-ctx tile, query-half). A (context) fragments resident
// in VGPRs for full K=256; B (query) chunks 128 rows x 128 halfs (32 KB)
// double-buffered via global_load_lds. 2 blocks/CU so barrier drains of one
// block overlap the other block's MFMA.
// XOR-16 swizzle: 16B group g of row r stored at pos g^(r&15) -> frag
// ds_read_b128 is conflict-free (2-way max).
// Writes partial max sp[b][nh][c] over this block's 1024 queries.
__global__ __launch_bounds__(256, 2)
void gemm_max_kernel(const _Float16* __restrict__ qf,
                     const _Float16* __restrict__ cf,
                     float* __restrict__ sp) {
    __shared__ __align__(16) _Float16 Buf[2][128 * 128];   // 2 x 32 KB
    __shared__ float red[2][128];

    const int mt = blockIdx.x;   // context tile 0..31
    const int nh = blockIdx.y;   // query half 0..1
    const int b  = blockIdx.z;   // batch 0..7

    const int tid  = threadIdx.x;
    const int lane = tid & 63;
    const int wave = tid >> 6;
    const int wm   = wave >> 1;  // ctx half within 128
    const int wn   = wave & 1;   // query half within 128
    const int quad = lane >> 4;
    const int l15  = lane & 15;

    const _Float16* Ag = cf + ((size_t)b * LC + (size_t)mt * 128) * DD;
    const _Float16* Bg = qf + ((size_t)b * LQ + (size_t)nh * 1024) * DD;

    // staging: pass p covers rows p*16..p*16+15; thread t -> row p*16+(t>>4),
    // stores LDS group (t&15), fetches global group (t&15)^((t>>4)&15).
    const int g_glob = (tid & 15) ^ ((tid >> 4) & 15);

    // src points at tile base + kc*128 halfs (row stride DD)
    #define STAGE(src, bufi)                                                       \
        {                                                                          \
            const _Float16* _s = (src);                                            \
            _Pragma("unroll")                                                      \
            for (int p = 0; p < 8; ++p)                                            \
                gload_lds16(_s + ((size_t)(p * 16 + (tid >> 4))) * DD + g_glob * 8,\
                            (char*)Buf[bufi] + p * 4096 + tid * 16);               \
        }

    // ---- prologue: A fragments -> registers (2 chunks of 128 halfs)
    f16x8 af[4][8];   // [mi][ks], k = ks*32 + quad*8
    STAGE(Ag, 0);
    __syncthreads();                       // A chunk 0 landed
    STAGE(Ag + 128, 1);
#pragma unroll
    for (int ksl = 0; ksl < 4; ++ksl)
#pragma unroll
        for (int mi = 0; mi < 4; ++mi) {
            const int row = wm * 64 + mi * 16 + l15;
            const int pos = (ksl * 4 + quad) ^ (row & 15);
            af[mi][ksl] = *(const f16x8*)((const char*)Buf[0] + row * 256 + pos * 16);
        }
    __syncthreads();                       // A chunk 1 landed; Buf[0] free
    STAGE(Bg, 0);                          // B chunk i=0 -> Buf[0]
#pragma unroll
    for (int ksl = 0; ksl < 4; ++ksl)
#pragma unroll
        for (int mi = 0; mi < 4; ++mi) {
            const int row = wm * 64 + mi * 16 + l15;
            const int pos = (ksl * 4 + quad) ^ (row & 15);
            af[mi][4 + ksl] = *(const f16x8*)((const char*)Buf[1] + row * 256 + pos * 16);
        }

    float rm[4][4];
#pragma unroll
    for (int mi = 0; mi < 4; ++mi)
#pragma unroll
        for (int r = 0; r < 4; ++r)
            rm[mi][r] = -3.4e38f;

    // ---- main loop: 8 query tiles x 2 K-chunks
#pragma unroll 1
    for (int nt = 0; nt < 8; ++nt) {
        f32x4 acc[4][4];
#pragma unroll
        for (int mi = 0; mi < 4; ++mi)
#pragma unroll
            for (int ni = 0; ni < 4; ++ni)
                acc[mi][ni] = (f32x4)0.0f;

#pragma unroll
        for (int kc = 0; kc < 2; ++kc) {
            const int i = nt * 2 + kc;
            __syncthreads();               // chunk i landed; other buf's reads done
            if (i < 15) {
                const int ntn = (i + 1) >> 1;
                const int kcn = (i + 1) & 1;
                STAGE(Bg + (size_t)ntn * 128 * DD + kcn * 128, (i + 1) & 1);
            }
#pragma unroll
            for (int ksl = 0; ksl < 4; ++ksl) {
                f16x8 bf[4];
#pragma unroll
                for (int ni = 0; ni < 4; ++ni) {
                    const int row = wn * 64 + ni * 16 + l15;
                    const int pos = (ksl * 4 + quad) ^ (row & 15);
                    bf[ni] = *(const f16x8*)((const char*)Buf[i & 1] + row * 256 + pos * 16);
                }
#pragma unroll
                for (int mi = 0; mi < 4; ++mi)
#pragma unroll
                    for (int ni = 0; ni < 4; ++ni)
                        acc[mi][ni] = __builtin_amdgcn_mfma_f32_16x16x32_f16(
                            af[mi][kc * 4 + ksl], bf[ni], acc[mi][ni], 0, 0, 0);
            }
        }
        // fold this tile's contribution into the running row max
#pragma unroll
        for (int mi = 0; mi < 4; ++mi)
#pragma unroll
            for (int r = 0; r < 4; ++r)
                rm[mi][r] = fmaxf(rm[mi][r],
                                  fmaxf(fmaxf(acc[mi][0][r], acc[mi][1][r]),
                                        fmaxf(acc[mi][2][r], acc[mi][3][r])));
    }

    // ---- epilogue: reduce over 16 col lanes, then the two wn halves
#pragma unroll
    for (int sh = 1; sh <= 8; sh <<= 1)
#pragma unroll
        for (int mi = 0; mi < 4; ++mi)
#pragma unroll
            for (int r = 0; r < 4; ++r)
                rm[mi][r] = fmaxf(rm[mi][r], __shfl_xor(rm[mi][r], sh, 64));

    if (l15 == 0) {
#pragma unroll
        for (int mi = 0; mi < 4; ++mi)
#pragma unroll
            for (int r = 0; r < 4; ++r)
                red[wn][wm * 64 + mi * 16 + quad * 4 + r] = rm[mi][r];
    }
    __syncthreads();
    if (tid < 128)
        sp[((size_t)b * 2 + nh) * LC + mt * 128 + tid] = fmaxf(red[0][tid], red[1][tid]);
    #undef STAGE
}

// One block per batch: reduce the 2 partial maxes, softmax over 4096 contexts
// (in LDS, unnormalized), then weighted context sum -> out[b][0][:].
__global__ __launch_bounds__(1024)
void softmax_out_kernel(const float* __restrict__ sp,
                        const _Float16* __restrict__ cf,
                        float* __restrict__ out) {
    __shared__ float pr[4096];
    __shared__ float part[4][256];
    __shared__ float redm[16], reds[16];

    const int b    = blockIdx.x;
    const int tid  = threadIdx.x;
    const int lane = tid & 63;
    const int wave = tid >> 4 >> 2;   // tid >> 6

    float sv[4];
    float lmax = -3.4e38f;
#pragma unroll
    for (int j = 0; j < 4; ++j) {
        const int c = tid + j * 1024;
        const float v = fmaxf(sp[((size_t)b * 2 + 0) * LC + c],
                              sp[((size_t)b * 2 + 1) * LC + c]);
        sv[j] = v;
        lmax  = fmaxf(lmax, v);
    }
#pragma unroll
    for (int sh = 1; sh < 64; sh <<= 1)
        lmax = fmaxf(lmax, __shfl_xor(lmax, sh, 64));
    if (lane == 0) redm[wave] = lmax;
    __syncthreads();
    float M = redm[0];
#pragma unroll
    for (int w = 1; w < 16; ++w) M = fmaxf(M, redm[w]);

    float lsum = 0.f;
#pragma unroll
    for (int j = 0; j < 4; ++j) {
        const float e = __expf(sv[j] - M);
        pr[tid + j * 1024] = e;
        lsum += e;
    }
#pragma unroll
    for (int sh = 1; sh < 64; sh <<= 1)
        lsum += __shfl_xor(lsum, sh, 64);
    if (lane == 0) reds[wave] = lsum;
    __syncthreads();          // pr[] complete + reds visible
    float S = 0.f;
#pragma unroll
    for (int w = 0; w < 16; ++w) S += reds[w];
    const float inv = 1.f / S;

    // weighted sum: group g handles contexts [g*1024, g*1024+1024)
    const int d = tid & 255;
    const int g = tid >> 8;
    const _Float16* cb = cf + (((size_t)b * LC) + (size_t)g * 1024) * DD + d;
    const float* pg = pr + g * 1024;
    float acc = 0.f;
#pragma unroll 8
    for (int i = 0; i < 1024; ++i)
        acc += pg[i] * (float)cb[(size_t)i * DD];
    part[g][d] = acc;
    __syncthreads();
    if (tid < 256)
        out[b * DD + tid] =
            (part[0][tid] + part[1][tid] + part[2][tid] + part[3][tid]) * inv;
}

extern "C" void kernel_launch(void* const* d_in, const int* in_sizes, int n_in,
                              void* d_out, int out_size, void* d_ws, size_t ws_size,
                              hipStream_t stream) {
    const float* q   = (const float*)d_in[0];   // [8, 2048, 256] f32
    const float* ctx = (const float*)d_in[1];   // [8, 4096, 256] f32
    float* out = (float*)d_out;                 // [8, 1, 256] f32

    // ws layout (bytes):
    //   qf @ 0        : 8*2048*256*2 =  8,388,608
    //   cf @ 8388608  : 8*4096*256*2 = 16,777,216
    //   sp @ 25165824 : 8*2*4096*4   =    262,144   (partial maxes per query-half)
    char* ws = (char*)d_ws;
    _Float16* qf = (_Float16*)(ws);
    _Float16* cf = (_Float16*)(ws + 8388608);
    float* sp    = (float*)(ws + 25165824);

    convert_all<<<6144, 256, 0, stream>>>(q, ctx, qf, cf);
    gemm_max_kernel<<<dim3(32, 2, 8), 256, 0, stream>>>(qf, cf, sp);
    softmax_out_kernel<<<8, 1024, 0, stream>>>(sp, cf, out);
}